// Round 9
// baseline (1314.031 us; speedup 1.0000x reference)
//
#include <hip/hip_runtime.h>

#define NV   200000      // occupied voxels
#define CC   128         // channels
#define KOFF 27          // 3x3x3 offsets

typedef unsigned short u16;
typedef __attribute__((ext_vector_type(4))) float f32x4;
typedef __attribute__((ext_vector_type(8))) short bf16x8;

__device__ __forceinline__ u16 f2bf(float f) {
    unsigned u = __float_as_uint(f);
    u += 0x7fffu + ((u >> 16) & 1u);          // RNE
    return (u16)(u >> 16);
}

// global -> LDS direct DMA, 16B per lane; LDS dest = uniform base + lane*16
#define GLOAD16(gp, lp)                                                        \
    __builtin_amdgcn_global_load_lds(                                          \
        (const __attribute__((address_space(1))) void*)(gp),                   \
        (__attribute__((address_space(3))) void*)(lp), 16, 0, 0)

// counted waits; sched_barrier pins following ops below the wait (rule #18)
#define WAITV8()                                                               \
    do { asm volatile("s_waitcnt vmcnt(8)" ::: "memory");                      \
         __builtin_amdgcn_sched_barrier(0); } while (0)
#define WAITV4()                                                               \
    do { asm volatile("s_waitcnt vmcnt(4)" ::: "memory");                      \
         __builtin_amdgcn_sched_barrier(0); } while (0)
#define WAITV0()                                                               \
    do { asm volatile("s_waitcnt vmcnt(0)" ::: "memory");                      \
         __builtin_amdgcn_sched_barrier(0); } while (0)

// ---------------------------------------------------------------------------
// gmap[k][i] = input row feeding output row i at offset k, or -1.
// out_idx entries are distinct per k, so this scatter is race-free.
__global__ void gmap_kernel(const int* __restrict__ iin,
                            const int* __restrict__ iout,
                            int* __restrict__ gmap) {
    int t = blockIdx.x * 256 + threadIdx.x;
    if (t >= KOFF * NV) return;
    int o = iout[t];
    if (o < NV) {
        int k = t / NV;
        gmap[k * NV + o] = iin[t];
    }
}

// fp32 -> bf16, 4 elems/thread
__global__ void cvt_kernel(const float* __restrict__ src,
                           u16* __restrict__ dst, int n4) {
    int i = blockIdx.x * 256 + threadIdx.x;
    if (i >= n4) return;
    float4 v = ((const float4*)src)[i];
    ushort4 o;
    o.x = f2bf(v.x); o.y = f2bf(v.y); o.z = f2bf(v.z); o.w = f2bf(v.w);
    ((ushort4*)dst)[i] = o;
}

// Pack W[k][kpos][col] fp32 into fragment-linear bf16:
// Wp[(k*nks+ks)*8 + cf][lane][j] = W[k][ks*32 + (lane>>4)*8 + j][cf*16 + (lane&15)]
__global__ void packw_kernel(const float* __restrict__ W,
                             u16* __restrict__ Wp, int cin, int total) {
    int t = blockIdx.x * 256 + threadIdx.x;
    if (t >= total) return;
    int j  = t & 7;
    int l  = (t >> 3) & 63;
    int cf = (t >> 9) & 7;
    int sk = t >> 12;                 // k*nks + ks
    int nks = cin >> 5;
    int k  = sk / nks;
    int ks = sk - k * nks;
    int kpos = ks * 32 + (l >> 4) * 8 + j;
    int col  = cf * 16 + (l & 15);
    Wp[t] = f2bf(W[((size_t)k * cin + kpos) * CC + col]);
}

// ---------------------------------------------------------------------------
// Gathered sparse conv: out[i] = bias + sum_k feat[gmap[k][i]] @ W[k]
// 128x128 tile / block, 4 waves (64x64 each), BK=32.
// Ring-4 LDS (80 KiB -> 2 blocks/CU), staging distance 3, gather indices in
// an LDS table (gmT, glds-preloaded once) so the main-loop VMEM FIFO holds
// ONLY global_load_lds ops (no register results -> compiler inserts no vmcnt
// in the loop). One raw s_barrier + one counted vmcnt(8) per K-step; the
// glds queue is never drained until the tail (exact FIFO-derived 8/4/0).
template <int NKS, int ACT, int OUT16>
__global__ __launch_bounds__(256, 2)
void conv_kernel(const u16* __restrict__ f0, const u16* __restrict__ f1,
                 const u16* __restrict__ Wp, const float* __restrict__ bias,
                 const int* __restrict__ gmap, const u16* __restrict__ zrow,
                 float* __restrict__ out32, u16* __restrict__ out16) {
    constexpr int NSTEP = KOFF * NKS;       // 108 or 216

    // A: 512 chunks of 16B per buffer; chunk slot = row*4 + (c ^ ((row>>1)&3))
    __shared__ u16 Ab[4][4096];             // 4 x 8 KiB
    // B: 8 col-frags x 64 lanes x 16B per buffer (fragment-linear)
    __shared__ u16 Bb[4][8][64][8];         // 4 x 8 KiB
    __shared__ int gmT[4096];               // 16 KiB: gmT[k*128+row], k<27

    const int tid = threadIdx.x;
    const int l   = tid & 63;
    const int w   = tid >> 6;
    const int wr  = w >> 1, wc = w & 1;
    const int r0  = blockIdx.x * 128;

    // A staging geometry (r4): wave w issues instrs j=2w,2w+1; instr j covers
    // slots j*64+l -> row = j*16 + (l>>2), source chunk = (l&3)^((l>>3)&3)
    const int qA  = (l & 3) ^ ((l >> 3) & 3);
    const int rA0 = 32 * w + (l >> 2);
    const int rA1 = rA0 + 16;

    float bcol[4];
#pragma unroll
    for (int c = 0; c < 4; ++c) bcol[c] = bias[wc * 64 + c * 16 + (l & 15)];

    f32x4 acc[4][4] = {};

    // ---- preload gmT: chunk c (4 ints) <- gmap[min(c>>5,26)*NV + r0 + (c*4)&127]
    // (gmap is padded with 512 sentinel (-1) rows, so r0+row reads are safe;
    //  k>26 chunks are harmless duplicates, never read back)
#pragma unroll
    for (int p = 0; p < 4; ++p) {
        int c = p * 256 + w * 64 + l;
        int k = c >> 5; if (k > 26) k = 26;
        const int* src = gmap + (size_t)k * NV + r0 + ((c * 4) & 127);
        GLOAD16(src, (char*)gmT + (size_t)(p * 256 + w * 64) * 16);
    }
    WAITV0();
    __builtin_amdgcn_s_barrier();           // gmT visible to all waves

    auto idxrd = [&](int s, int& g0, int& g1) {
        int k = s / NKS;
        g0 = gmT[k * 128 + rA0];
        g1 = gmT[k * 128 + rA1];
    };

    auto stage = [&](int s, int buf, int g0, int g1) {
        int ks = s % NKS;
        const u16* base;
        int slice;
        if constexpr (NKS == 8) {                 // concat: slices 0-3 = x, 4-7 = h
            base  = (ks < 4) ? f0 : f1;
            slice = (ks & 3) * 32;
        } else {
            base  = f0;
            slice = ks * 32;
        }
        const u16* sA0 = (g0 >= 0) ? base + (size_t)g0 * CC + slice + qA * 8
                                   : zrow + qA * 8;
        const u16* sA1 = (g1 >= 0) ? base + (size_t)g1 * CC + slice + qA * 8
                                   : zrow + qA * 8;
        GLOAD16(sA0, &Ab[buf][(2 * w) * 512]);
        GLOAD16(sA1, &Ab[buf][(2 * w + 1) * 512]);
        int k = s / NKS;
        const u16* wsrc = Wp + (((size_t)(k * NKS + ks) * 8 + 2 * w) * 512) + l * 8;
        GLOAD16(wsrc,       &Bb[buf][2 * w][0][0]);
        GLOAD16(wsrc + 512, &Bb[buf][2 * w + 1][0][0]);
    };

    auto compute = [&](int buf) {
        bf16x8 a[4], b[4];
        const int q = l >> 4;
#pragma unroll
        for (int rf = 0; rf < 4; ++rf) {
            int rl = wr * 64 + rf * 16 + (l & 15);
            int ci = rl * 4 + (q ^ ((rl >> 1) & 3));
            a[rf] = *(const bf16x8*)&Ab[buf][ci * 8];
        }
#pragma unroll
        for (int c = 0; c < 4; ++c)
            b[c] = *(const bf16x8*)&Bb[buf][wc * 4 + c][l][0];
        __builtin_amdgcn_s_setprio(1);
#pragma unroll
        for (int rf = 0; rf < 4; ++rf)
#pragma unroll
            for (int c = 0; c < 4; ++c)
                acc[rf][c] = __builtin_amdgcn_mfma_f32_16x16x32_bf16(
                    a[rf], b[c], acc[rf][c], 0, 0, 0);
        __builtin_amdgcn_s_setprio(0);
    };

    // ---- prologue: stage 0,1,2 (12 glds in flight), prefetch indices 3,4
    {
        int t0, t1;
        idxrd(0, t0, t1); stage(0, 0, t0, t1);
        idxrd(1, t0, t1); stage(1, 1, t0, t1);
        idxrd(2, t0, t1); stage(2, 2, t0, t1);
    }
    int gC0, gC1, gN0, gN1;
    idxrd(3, gC0, gC1);
    idxrd(4, gN0, gN1);

    for (int t = 0; t < NSTEP; ++t) {
        // FIFO at top of t: [st(t):4, st(t+1):4?, st(t+2):4?]
        if (t + 2 < NSTEP)      { WAITV8(); }   // retire st(t)
        else if (t + 1 < NSTEP) { WAITV4(); }
        else                    { WAITV0(); }
        __builtin_amdgcn_s_barrier();            // st(t) visible to all waves
        if (t + 3 < NSTEP) stage(t + 3, (t + 3) & 3, gC0, gC1);
        gC0 = gN0; gC1 = gN1;
        if (t + 5 < NSTEP) idxrd(t + 5, gN0, gN1);   // prefetch next indices
        compute(t & 3);
    }

    // epilogue: C/D layout col=lane&15, row=(lane>>4)*4+reg  [m89-verified]
#pragma unroll
    for (int rf = 0; rf < 4; ++rf) {
        int rbase = r0 + wr * 64 + rf * 16 + (l >> 4) * 4;
#pragma unroll
        for (int i = 0; i < 4; ++i) {
            int row = rbase + i;
            if (row < NV) {
#pragma unroll
                for (int c = 0; c < 4; ++c) {
                    float v = acc[rf][c][i] + bcol[c];
                    if constexpr (ACT) v = fmaxf(v, 0.f);
                    int col = wc * 64 + c * 16 + (l & 15);
                    if constexpr (OUT16) out16[(size_t)row * CC + col] = f2bf(v);
                    else                 out32[(size_t)row * CC + col] = v;
                }
            }
        }
    }
}

// ---------------------------------------------------------------------------
extern "C" void kernel_launch(void* const* d_in, const int* in_sizes, int n_in,
                              void* d_out, int out_size, void* d_ws, size_t ws_size,
                              hipStream_t stream) {
    (void)in_sizes; (void)n_in; (void)out_size; (void)ws_size;
    const float* xF  = (const float*)d_in[0];
    const float* xgF = (const float*)d_in[1];
    const float* W0  = (const float*)d_in[2];
    const float* b0  = (const float*)d_in[3];
    const float* W1  = (const float*)d_in[4];
    const float* b1  = (const float*)d_in[5];
    const float* W2  = (const float*)d_in[6];
    const float* b2  = (const float*)d_in[7];
    const int* iin   = (const int*)d_in[8];
    const int* iout  = (const int*)d_in[9];
    float* out = (float*)d_out;
    char* ws = (char*)d_ws;

    size_t off = 0;
    int* gmap  = (int*)(ws + off);  off += ((size_t)KOFF * NV + 512) * 4;  // +pad (-1)
    u16* zrow  = (u16*)(ws + off);  off += 256;
    u16* F0    = (u16*)(ws + off);  off += (size_t)NV * CC * 2;     // xg16 -> h1
    u16* F1    = (u16*)(ws + off);  off += (size_t)NV * CC * 2;     // h0
    u16* F2    = (u16*)(ws + off);  off += (size_t)NV * CC * 2;     // x16
    u16* WP0   = (u16*)(ws + off);  off += (size_t)KOFF * 128 * 128 * 2;
    u16* WP1   = (u16*)(ws + off);  off += (size_t)KOFF * 128 * 128 * 2;
    u16* WP2   = (u16*)(ws + off);  off += (size_t)KOFF * 256 * 128 * 2;
    // total ~178.7 MB of d_ws

    (void)hipMemsetAsync(gmap, 0xFF, ((size_t)KOFF * NV + 512) * 4, stream);  // -1
    (void)hipMemsetAsync(zrow, 0, 256, stream);

    gmap_kernel<<<(KOFF * NV + 255) / 256, 256, 0, stream>>>(iin, iout, gmap);
    cvt_kernel<<<(NV * CC / 4 + 255) / 256, 256, 0, stream>>>(xgF, F0, NV * CC / 4);
    cvt_kernel<<<(NV * CC / 4 + 255) / 256, 256, 0, stream>>>(xF,  F2, NV * CC / 4);
    packw_kernel<<<(KOFF * 128 * 128 + 255) / 256, 256, 0, stream>>>(W0, WP0, 128, KOFF * 128 * 128);
    packw_kernel<<<(KOFF * 128 * 128 + 255) / 256, 256, 0, stream>>>(W1, WP1, 128, KOFF * 128 * 128);
    packw_kernel<<<(KOFF * 256 * 128 + 255) / 256, 256, 0, stream>>>(W2, WP2, 256, KOFF * 256 * 128);

    const int NB = (NV + 127) / 128;   // 1563
    // conv0: h0 = xg (*) W0 + b0            -> F1 (bf16)
    conv_kernel<4, 0, 1><<<NB, 256, 0, stream>>>(F0, F0, WP0, b0, gmap, zrow, nullptr, F1);
    // conv1: h1 = relu(h0 (*) W1 + b1)      -> F0 (bf16)
    conv_kernel<4, 1, 1><<<NB, 256, 0, stream>>>(F1, F1, WP1, b1, gmap, zrow, nullptr, F0);
    // conv2: out = [x | h1] (*) W2 + b2     -> d_out (fp32)
    conv_kernel<8, 0, 0><<<NB, 256, 0, stream>>>(F2, F0, WP2, b2, gmap, zrow, out, nullptr);
}

// Round 10
// 747.551 us; speedup vs baseline: 1.7578x; 1.7578x over previous
//
#include <hip/hip_runtime.h>

#define NV   200000      // occupied voxels
#define CC   128         // channels
#define KOFF 27          // 3x3x3 offsets

typedef unsigned short u16;
typedef __attribute__((ext_vector_type(4))) float f32x4;
typedef __attribute__((ext_vector_type(8))) short bf16x8;

__device__ __forceinline__ u16 f2bf(float f) {
    unsigned u = __float_as_uint(f);
    u += 0x7fffu + ((u >> 16) & 1u);          // RNE
    return (u16)(u >> 16);
}

// global -> LDS direct DMA, 16B per lane; LDS dest = uniform base + lane*16
#define GLOAD16(gp, lp)                                                        \
    __builtin_amdgcn_global_load_lds(                                          \
        (const __attribute__((address_space(1))) void*)(gp),                   \
        (__attribute__((address_space(3))) void*)(lp), 16, 0, 0)

// ---------------------------------------------------------------------------
// gmap[k][i] = input row feeding output row i at offset k, or -1.
// out_idx entries are distinct per k, so this scatter is race-free.
__global__ void gmap_kernel(const int* __restrict__ iin,
                            const int* __restrict__ iout,
                            int* __restrict__ gmap) {
    int t = blockIdx.x * 256 + threadIdx.x;
    if (t >= KOFF * NV) return;
    int o = iout[t];
    if (o < NV) {
        int k = t / NV;
        gmap[k * NV + o] = iin[t];
    }
}

// fp32 -> bf16, 4 elems/thread
__global__ void cvt_kernel(const float* __restrict__ src,
                           u16* __restrict__ dst, int n4) {
    int i = blockIdx.x * 256 + threadIdx.x;
    if (i >= n4) return;
    float4 v = ((const float4*)src)[i];
    ushort4 o;
    o.x = f2bf(v.x); o.y = f2bf(v.y); o.z = f2bf(v.z); o.w = f2bf(v.w);
    ((ushort4*)dst)[i] = o;
}

// Pack W[k][kpos][col] fp32 into fragment-linear bf16:
// Wp[(k*nks+ks)*8 + cf][lane][j] = W[k][ks*32 + (lane>>4)*8 + j][cf*16 + (lane&15)]
__global__ void packw_kernel(const float* __restrict__ W,
                             u16* __restrict__ Wp, int cin, int total) {
    int t = blockIdx.x * 256 + threadIdx.x;
    if (t >= total) return;
    int j  = t & 7;
    int l  = (t >> 3) & 63;
    int cf = (t >> 9) & 7;
    int sk = t >> 12;                 // k*nks + ks
    int nks = cin >> 5;
    int k  = sk / nks;
    int ks = sk - k * nks;
    int kpos = ks * 32 + (l >> 4) * 8 + j;
    int col  = cf * 16 + (l & 15);
    Wp[t] = f2bf(W[((size_t)k * cin + kpos) * CC + col]);
}

// ---------------------------------------------------------------------------
// Gathered sparse conv: out[i] = bias + sum_k feat[gmap[k][i]] @ W[k]
// 128x128 tile / block, 4 waves (64x64 each), BK=32, double-buffered LDS
// (r4 champion structure, 915 TF-equiv = the m97-family ceiling).
// Gather indices reloaded ONLY when the offset k changes (every NKS steps);
// they are invariant in between (r10 tweak: removes 75-87% of index loads).
template <int NKS, int ACT, int OUT16>
__global__ __launch_bounds__(256, 2)
void conv_kernel(const u16* __restrict__ f0, const u16* __restrict__ f1,
                 const u16* __restrict__ Wp, const float* __restrict__ bias,
                 const int* __restrict__ gmap, const u16* __restrict__ zrow,
                 float* __restrict__ out32, u16* __restrict__ out16) {
    constexpr int NSTEP = KOFF * NKS;

    // A: 512 chunks of 16B per buffer; chunk slot = row*4 + (c ^ ((row>>1)&3))
    __shared__ u16 Ab[2][512 * 8];
    // B: 8 col-frags x 64 lanes x 16B per buffer (fragment-linear)
    __shared__ u16 Bb[2][8][64][8];

    const int tid = threadIdx.x;
    const int l   = tid & 63;
    const int w   = tid >> 6;
    const int wr  = w >> 1, wc = w & 1;
    const int r0  = blockIdx.x * 128;

    // A staging geometry: wave w issues instrs j=2w,2w+1; instr j covers
    // slots j*64+l -> row = j*16 + (l>>2), source chunk = (l&3)^((l>>3)&3)
    const int qA  = (l & 3) ^ ((l >> 3) & 3);
    const int rA0 = 32 * w + (l >> 2);
    const int rA1 = rA0 + 16;

    float bcol[4];
#pragma unroll
    for (int c = 0; c < 4; ++c) bcol[c] = bias[wc * 64 + c * 16 + (l & 15)];

    f32x4 acc[4][4] = {};

    int gA, gB;                                   // gather rows for current k
    auto loadGmap = [&](int s) {
        int k = s / NKS;
        int ra = r0 + rA0, rb = r0 + rA1;
        gA = (ra < NV) ? gmap[k * NV + ra] : -1;
        gB = (rb < NV) ? gmap[k * NV + rb] : -1;
    };

    auto stage = [&](int s, int buf) {
        int k = s / NKS, ks = s - k * NKS;
        const u16* base;
        int slice;
        if constexpr (NKS == 8) {                 // concat: slices 0-3 = x, 4-7 = h
            base  = (ks < 4) ? f0 : f1;
            slice = (ks & 3) * 32;
        } else {
            base  = f0;
            slice = ks * 32;
        }
        const u16* sA0 = (gA >= 0) ? base + (size_t)gA * CC + slice + qA * 8
                                   : zrow + qA * 8;
        const u16* sA1 = (gB >= 0) ? base + (size_t)gB * CC + slice + qA * 8
                                   : zrow + qA * 8;
        GLOAD16(sA0, &Ab[buf][(2 * w) * 64 * 8]);
        GLOAD16(sA1, &Ab[buf][(2 * w + 1) * 64 * 8]);
        const u16* wsrc = Wp + (((size_t)(k * NKS + ks) * 8 + 2 * w) * 512) + l * 8;
        GLOAD16(wsrc,       &Bb[buf][2 * w][0][0]);
        GLOAD16(wsrc + 512, &Bb[buf][2 * w + 1][0][0]);
    };

    auto compute = [&](int buf) {
        bf16x8 a[4], b[4];
        const int q = l >> 4;
#pragma unroll
        for (int rf = 0; rf < 4; ++rf) {
            int rl = wr * 64 + rf * 16 + (l & 15);
            int ci = rl * 4 + (q ^ ((rl >> 1) & 3));
            a[rf] = *(const bf16x8*)&Ab[buf][ci * 8];
        }
#pragma unroll
        for (int c = 0; c < 4; ++c)
            b[c] = *(const bf16x8*)&Bb[buf][wc * 4 + c][l][0];
#pragma unroll
        for (int rf = 0; rf < 4; ++rf)
#pragma unroll
            for (int c = 0; c < 4; ++c)
                acc[rf][c] = __builtin_amdgcn_mfma_f32_16x16x32_bf16(
                    a[rf], b[c], acc[rf][c], 0, 0, 0);
    };

    loadGmap(0);                                  // indices for offset k=0
    stage(0, 0);
    __syncthreads();

    int cur = 0;
    for (int s = 0; s < NSTEP; ++s) {
        if (s + 1 < NSTEP) {
            stage(s + 1, cur ^ 1);                // uses g(k of s+1): k changes
                                                  // only at (s+1)%NKS==0, and
                                                  // the reload below ran then
            if (s + 2 < NSTEP && ((s + 2) % NKS) == 0)
                loadGmap(s + 2);                  // prefetch indices for next k
        }
        compute(cur);
        __syncthreads();                          // vmcnt(0)+lgkmcnt(0)+barrier
        cur ^= 1;
    }

    // epilogue: C/D layout col=lane&15, row=(lane>>4)*4+reg  [m89-verified]
#pragma unroll
    for (int rf = 0; rf < 4; ++rf) {
        int rbase = r0 + wr * 64 + rf * 16 + (l >> 4) * 4;
#pragma unroll
        for (int i = 0; i < 4; ++i) {
            int row = rbase + i;
            if (row < NV) {
#pragma unroll
                for (int c = 0; c < 4; ++c) {
                    float v = acc[rf][c][i] + bcol[c];
                    if constexpr (ACT) v = fmaxf(v, 0.f);
                    int col = wc * 64 + c * 16 + (l & 15);
                    if constexpr (OUT16) out16[(size_t)row * CC + col] = f2bf(v);
                    else                 out32[(size_t)row * CC + col] = v;
                }
            }
        }
    }
}

// ---------------------------------------------------------------------------
extern "C" void kernel_launch(void* const* d_in, const int* in_sizes, int n_in,
                              void* d_out, int out_size, void* d_ws, size_t ws_size,
                              hipStream_t stream) {
    (void)in_sizes; (void)n_in; (void)out_size; (void)ws_size;
    const float* xF  = (const float*)d_in[0];
    const float* xgF = (const float*)d_in[1];
    const float* W0  = (const float*)d_in[2];
    const float* b0  = (const float*)d_in[3];
    const float* W1  = (const float*)d_in[4];
    const float* b1  = (const float*)d_in[5];
    const float* W2  = (const float*)d_in[6];
    const float* b2  = (const float*)d_in[7];
    const int* iin   = (const int*)d_in[8];
    const int* iout  = (const int*)d_in[9];
    float* out = (float*)d_out;
    char* ws = (char*)d_ws;

    size_t off = 0;
    int* gmap  = (int*)(ws + off);  off += (size_t)KOFF * NV * 4;   // 21.6 MB
    u16* zrow  = (u16*)(ws + off);  off += 256;
    u16* F0    = (u16*)(ws + off);  off += (size_t)NV * CC * 2;     // xg16 -> h1
    u16* F1    = (u16*)(ws + off);  off += (size_t)NV * CC * 2;     // h0
    u16* F2    = (u16*)(ws + off);  off += (size_t)NV * CC * 2;     // x16
    u16* WP0   = (u16*)(ws + off);  off += (size_t)KOFF * 128 * 128 * 2;
    u16* WP1   = (u16*)(ws + off);  off += (size_t)KOFF * 128 * 128 * 2;
    u16* WP2   = (u16*)(ws + off);  off += (size_t)KOFF * 256 * 128 * 2;
    // total ~178.7 MB of d_ws

    (void)hipMemsetAsync(gmap, 0xFF, (size_t)KOFF * NV * 4, stream);  // -1
    (void)hipMemsetAsync(zrow, 0, 256, stream);

    gmap_kernel<<<(KOFF * NV + 255) / 256, 256, 0, stream>>>(iin, iout, gmap);
    cvt_kernel<<<(NV * CC / 4 + 255) / 256, 256, 0, stream>>>(xgF, F0, NV * CC / 4);
    cvt_kernel<<<(NV * CC / 4 + 255) / 256, 256, 0, stream>>>(xF,  F2, NV * CC / 4);
    packw_kernel<<<(KOFF * 128 * 128 + 255) / 256, 256, 0, stream>>>(W0, WP0, 128, KOFF * 128 * 128);
    packw_kernel<<<(KOFF * 128 * 128 + 255) / 256, 256, 0, stream>>>(W1, WP1, 128, KOFF * 128 * 128);
    packw_kernel<<<(KOFF * 256 * 128 + 255) / 256, 256, 0, stream>>>(W2, WP2, 256, KOFF * 256 * 128);

    const int NB = (NV + 127) / 128;   // 1563
    // conv0: h0 = xg (*) W0 + b0            -> F1 (bf16)
    conv_kernel<4, 0, 1><<<NB, 256, 0, stream>>>(F0, F0, WP0, b0, gmap, zrow, nullptr, F1);
    // conv1: h1 = relu(h0 (*) W1 + b1)      -> F0 (bf16)
    conv_kernel<4, 1, 1><<<NB, 256, 0, stream>>>(F1, F1, WP1, b1, gmap, zrow, nullptr, F0);
    // conv2: out = [x | h1] (*) W2 + b2     -> d_out (fp32)
    conv_kernel<8, 0, 0><<<NB, 256, 0, stream>>>(F2, F0, WP2, b2, gmap, zrow, out, nullptr);
}